// Round 1
// baseline (779.637 us; speedup 1.0000x reference)
//
#include <hip/hip_runtime.h>
#include <math.h>

#define S 4096
#define B 64
#define H 512
#define MAX_NSPLIT 32

// ---------------------------------------------------------------------------
// Kernel 1: v[b,j] = sum_i h_t[b,i] * W_a[i,j]   (v = h_t @ W_a, [B,H])
//           c0[b]  = b_a . h_t[b]
// grid = B blocks, 256 threads. Each thread computes v[b,t] and v[b,t+256].
// ---------------------------------------------------------------------------
__global__ __launch_bounds__(256) void prep_kernel(
    const float* __restrict__ h_t, const float* __restrict__ W_a,
    const float* __restrict__ b_a, float* __restrict__ v, float* __restrict__ c0)
{
    const int b = blockIdx.x;
    const int t = threadIdx.x;
    __shared__ float sh[H];
    __shared__ float red[256];

    float h0 = h_t[b * H + t];
    float h1 = h_t[b * H + 256 + t];
    sh[t] = h0;
    sh[256 + t] = h1;
    red[t] = b_a[t] * h0 + b_a[256 + t] * h1;
    __syncthreads();
    for (int off = 128; off; off >>= 1) {
        if (t < off) red[t] += red[t + off];
        __syncthreads();
    }

    float acc0 = 0.f, acc1 = 0.f;
#pragma unroll 8
    for (int i = 0; i < H; ++i) {
        float h = sh[i];
        acc0 = fmaf(h, W_a[i * H + t], acc0);
        acc1 = fmaf(h, W_a[i * H + 256 + t], acc1);
    }
    v[b * H + t] = acc0;
    v[b * H + 256 + t] = acc1;
    if (t == 0) c0[b] = red[0];
}

// ---------------------------------------------------------------------------
// Kernel 2: single streaming pass over encoder_hidden_states with online
// softmax. One wave per row (64 lanes x 8 floats = 512 = H). Each block
// handles one (b, chunk) pair; 4 waves round-robin over the chunk's rows.
// Writes per-(b,chunk) partial: [m, l, o[H]].
// ---------------------------------------------------------------------------
__global__ __launch_bounds__(256) void pass_kernel(
    const float* __restrict__ hs, const int* __restrict__ mask,
    const float* __restrict__ v, const float* __restrict__ c0,
    float* __restrict__ part, int nsplit, int rows)
{
    const int b = blockIdx.x % B;
    const int chunk = blockIdx.x / B;
    const int lane = threadIdx.x & 63;
    const int w = threadIdx.x >> 6;

    const float4 vlo = *(const float4*)&v[b * H + lane * 4];
    const float4 vhi = *(const float4*)&v[b * H + 256 + lane * 4];
    const float cc = c0[b];

    float m = -INFINITY, l = 0.f;
    float4 olo = {0.f, 0.f, 0.f, 0.f};
    float4 ohi = {0.f, 0.f, 0.f, 0.f};

    const int s0 = chunk * rows;
    for (int k = w; k < rows; k += 4) {
        const int s = s0 + k;
        if (mask[b * S + s] == 0) continue;  // log(0) = -inf -> weight 0
        const float* row = hs + ((size_t)s * B + b) * H;
        const float4 dlo = *(const float4*)&row[lane * 4];
        const float4 dhi = *(const float4*)&row[256 + lane * 4];

        float d = dlo.x * vlo.x + dlo.y * vlo.y + dlo.z * vlo.z + dlo.w * vlo.w
                + dhi.x * vhi.x + dhi.y * vhi.y + dhi.z * vhi.z + dhi.w * vhi.w;
#pragma unroll
        for (int off = 32; off; off >>= 1) d += __shfl_xor(d, off);
        const float score = d + cc;

        const float mn = fmaxf(m, score);
        const float p = __expf(score - mn);
        const float alpha = __expf(m - mn);  // m=-inf -> alpha=0, safe
        l = l * alpha + p;
        olo.x = olo.x * alpha + p * dlo.x;
        olo.y = olo.y * alpha + p * dlo.y;
        olo.z = olo.z * alpha + p * dlo.z;
        olo.w = olo.w * alpha + p * dlo.w;
        ohi.x = ohi.x * alpha + p * dhi.x;
        ohi.y = ohi.y * alpha + p * dhi.y;
        ohi.z = ohi.z * alpha + p * dhi.z;
        ohi.w = ohi.w * alpha + p * dhi.w;
        m = mn;
    }

    // combine the 4 waves of this block
    __shared__ float sm[4], sl[4];
    __shared__ __align__(16) float so[4][H];
    *(float4*)&so[w][lane * 4] = olo;
    *(float4*)&so[w][256 + lane * 4] = ohi;
    if (lane == 0) { sm[w] = m; sl[w] = l; }
    __syncthreads();

    const float M = fmaxf(fmaxf(sm[0], sm[1]), fmaxf(sm[2], sm[3]));
    float wt[4];
    float L = 0.f;
#pragma unroll
    for (int i = 0; i < 4; ++i) {
        wt[i] = (sl[i] > 0.f) ? __expf(sm[i] - M) : 0.f;  // guards M=-inf NaN
        L += sl[i] * wt[i];
    }
    const int t = threadIdx.x;
    float* P = part + (size_t)(b * nsplit + chunk) * (H + 2);
    const float O0 = so[0][t] * wt[0] + so[1][t] * wt[1]
                   + so[2][t] * wt[2] + so[3][t] * wt[3];
    const float O1 = so[0][256 + t] * wt[0] + so[1][256 + t] * wt[1]
                   + so[2][256 + t] * wt[2] + so[3][256 + t] * wt[3];
    P[2 + t] = O0;
    P[2 + 256 + t] = O1;
    if (t == 0) { P[0] = M; P[1] = L; }
}

// ---------------------------------------------------------------------------
// Kernel 3: combine partials -> c_t[b,:], cat=[c_t,h_t] in LDS, then
// out[b,i] = tanh(cat . W_r[i,:] + b_r[i]).
// grid = (B, 2): block (b, half) computes outputs i in [half*256, half*256+256).
// ---------------------------------------------------------------------------
__global__ __launch_bounds__(256) void final_kernel(
    const float* __restrict__ part, const float* __restrict__ h_t,
    const float* __restrict__ W_r, const float* __restrict__ b_r,
    float* __restrict__ out, int nsplit)
{
    const int b = blockIdx.x;
    const int half = blockIdx.y;
    const int t = threadIdx.x;
    __shared__ __align__(16) float cat[2 * H];

    float M = -INFINITY;
    for (int c = 0; c < nsplit; ++c)
        M = fmaxf(M, part[(size_t)(b * nsplit + c) * (H + 2)]);

    float L = 0.f, O0 = 0.f, O1 = 0.f;
    for (int c = 0; c < nsplit; ++c) {
        const float* P = part + (size_t)(b * nsplit + c) * (H + 2);
        const float lc = P[1];
        const float wc = (lc > 0.f) ? __expf(P[0] - M) : 0.f;
        L += lc * wc;
        O0 += P[2 + t] * wc;
        O1 += P[2 + 256 + t] * wc;
    }
    const float inv = 1.f / L;
    cat[t] = O0 * inv;
    cat[256 + t] = O1 * inv;
    cat[512 + t] = h_t[b * H + t];
    cat[768 + t] = h_t[b * H + 256 + t];
    __syncthreads();

    const int i = half * 256 + t;
    const float* wr = W_r + (size_t)i * (2 * H);
    float acc = b_r[i];
#pragma unroll 4
    for (int j = 0; j < 2 * H; j += 4) {
        const float4 wv = *(const float4*)&wr[j];
        acc += wv.x * cat[j] + wv.y * cat[j + 1]
             + wv.z * cat[j + 2] + wv.w * cat[j + 3];
    }
    out[b * H + i] = tanhf(acc);
}

// ---------------------------------------------------------------------------
extern "C" void kernel_launch(void* const* d_in, const int* in_sizes, int n_in,
                              void* d_out, int out_size, void* d_ws, size_t ws_size,
                              hipStream_t stream) {
    const float* hs  = (const float*)d_in[0];  // [S,B,H]
    const float* h_t = (const float*)d_in[1];  // [B,H]
    const int* mask  = (const int*)d_in[2];    // [B,S]
    const float* W_a = (const float*)d_in[3];  // [H,H]
    const float* b_a = (const float*)d_in[4];  // [H]
    const float* W_r = (const float*)d_in[5];  // [H,2H]
    const float* b_r = (const float*)d_in[6];  // [H]
    float* out = (float*)d_out;                // [B,H]
    float* ws = (float*)d_ws;

    // workspace: v[B*H] | c0[64] | partials[B*nsplit*(H+2)]
    int nsplit = MAX_NSPLIT;
    while (nsplit > 1) {
        size_t need = ((size_t)B * H + 64 + (size_t)B * nsplit * (H + 2)) * sizeof(float);
        if (need <= ws_size) break;
        nsplit >>= 1;
    }
    const int rows = S / nsplit;

    float* v = ws;
    float* c0 = ws + B * H;
    float* part = ws + B * H + 64;

    prep_kernel<<<B, 256, 0, stream>>>(h_t, W_a, b_a, v, c0);
    pass_kernel<<<B * nsplit, 256, 0, stream>>>(hs, mask, v, c0, part, nsplit, rows);
    final_kernel<<<dim3(B, 2), 256, 0, stream>>>(part, h_t, W_r, b_r, out, nsplit);
}

// Round 2
// 757.303 us; speedup vs baseline: 1.0295x; 1.0295x over previous
//
#include <hip/hip_runtime.h>
#include <math.h>

#define S 4096
#define B 64
#define H 512
#define NSPLIT 32
#define ROWS 128   // S / NSPLIT
#define TILE 8

// ---------------------------------------------------------------------------
// Kernel 1: v[b,j] = sum_i h_t[b,i] * W_a[i,j]  (v = h_t @ W_a, [B,H])
//           c0[b]  = b_a . h_t[b]
// grid = (B, 2): block (b, half) computes v[b, half*256 .. +256).
// ---------------------------------------------------------------------------
__global__ __launch_bounds__(256) void prep_kernel(
    const float* __restrict__ h_t, const float* __restrict__ W_a,
    const float* __restrict__ b_a, float* __restrict__ v, float* __restrict__ c0)
{
    const int b = blockIdx.x;
    const int half = blockIdx.y;
    const int t = threadIdx.x;
    const int j = half * 256 + t;
    __shared__ float sh[H];
    __shared__ float red[256];

    const float h0 = h_t[b * H + t];
    const float h1 = h_t[b * H + 256 + t];
    sh[t] = h0;
    sh[256 + t] = h1;
    if (half == 0) red[t] = b_a[t] * h0 + b_a[256 + t] * h1;
    __syncthreads();
    if (half == 0) {
        for (int off = 128; off; off >>= 1) {
            if (t < off) red[t] += red[t + off];
            __syncthreads();
        }
        if (t == 0) c0[b] = red[0];
    }

    float acc = 0.f;
#pragma unroll 8
    for (int i = 0; i < H; ++i)
        acc = fmaf(sh[i], W_a[i * H + j], acc);
    v[b * H + j] = acc;
}

// ---------------------------------------------------------------------------
// Kernel 2: streaming pass over hs with online softmax, 8-row register tiles.
// One wave per row-tile; block = (b, chunk) of 128 rows; 4 waves per block.
// Branchless masking: additive -inf penalty from LDS. Writes per-(b,chunk)
// partials SoA: partM/partL scalars + partO[H].
// ---------------------------------------------------------------------------
__global__ __launch_bounds__(256) void pass_kernel(
    const float* __restrict__ hs, const int* __restrict__ mask,
    const float* __restrict__ v, const float* __restrict__ c0,
    float* __restrict__ partM, float* __restrict__ partL,
    float* __restrict__ partO)
{
    const int b = blockIdx.x & (B - 1);
    const int chunk = blockIdx.x >> 6;
    const int lane = threadIdx.x & 63;
    const int w = threadIdx.x >> 6;
    const int s0 = chunk * ROWS;

    __shared__ float pen[ROWS];
    __shared__ float sm[4], sl[4];
    __shared__ __align__(16) float so[4][H];

    if (threadIdx.x < ROWS)
        pen[threadIdx.x] = mask[b * S + s0 + threadIdx.x] ? 0.f : -INFINITY;
    __syncthreads();

    const float4 vlo = *(const float4*)&v[b * H + lane * 4];
    const float4 vhi = *(const float4*)&v[b * H + 256 + lane * 4];
    const float cc = c0[b];

    float m = -INFINITY, l = 0.f;
    float4 olo = {0.f, 0.f, 0.f, 0.f};
    float4 ohi = {0.f, 0.f, 0.f, 0.f};

    for (int base = w * TILE; base < ROWS; base += 4 * TILE) {
        // --- 16 independent dwordx4 loads: 8 KB in flight per wave ---
        float4 rl[TILE], rh[TILE];
        const float* row0 = hs + ((size_t)(s0 + base) * B + b) * H;
#pragma unroll
        for (int r = 0; r < TILE; ++r) {
            const float* row = row0 + (size_t)r * (B * H);
            rl[r] = *(const float4*)&row[lane * 4];
            rh[r] = *(const float4*)&row[256 + lane * 4];
        }
        // --- 8 independent dot chains ---
        float d[TILE];
#pragma unroll
        for (int r = 0; r < TILE; ++r) {
            d[r] = rl[r].x * vlo.x + rl[r].y * vlo.y + rl[r].z * vlo.z + rl[r].w * vlo.w
                 + rh[r].x * vhi.x + rh[r].y * vhi.y + rh[r].z * vhi.z + rh[r].w * vhi.w;
        }
        // --- batched 64-lane butterfly reduce (48 independent shuffles) ---
#pragma unroll
        for (int off = 32; off; off >>= 1) {
#pragma unroll
            for (int r = 0; r < TILE; ++r) d[r] += __shfl_xor(d[r], off);
        }
        // --- tile-level online softmax (one rescale per 8 rows) ---
        float tmax = -INFINITY;
#pragma unroll
        for (int r = 0; r < TILE; ++r) {
            d[r] += cc + pen[base + r];
            tmax = fmaxf(tmax, d[r]);
        }
        const float mn = fmaxf(m, tmax);
        const float ms = (mn == -INFINITY) ? 0.f : mn;  // all-masked guard
        const float alpha = __expf(m - ms);
        float p[TILE], psum = 0.f;
#pragma unroll
        for (int r = 0; r < TILE; ++r) { p[r] = __expf(d[r] - ms); psum += p[r]; }
        l = l * alpha + psum;
        olo.x *= alpha; olo.y *= alpha; olo.z *= alpha; olo.w *= alpha;
        ohi.x *= alpha; ohi.y *= alpha; ohi.z *= alpha; ohi.w *= alpha;
#pragma unroll
        for (int r = 0; r < TILE; ++r) {
            olo.x = fmaf(p[r], rl[r].x, olo.x);
            olo.y = fmaf(p[r], rl[r].y, olo.y);
            olo.z = fmaf(p[r], rl[r].z, olo.z);
            olo.w = fmaf(p[r], rl[r].w, olo.w);
            ohi.x = fmaf(p[r], rh[r].x, ohi.x);
            ohi.y = fmaf(p[r], rh[r].y, ohi.y);
            ohi.z = fmaf(p[r], rh[r].z, ohi.z);
            ohi.w = fmaf(p[r], rh[r].w, ohi.w);
        }
        m = mn;
    }

    // --- combine the 4 waves of this block ---
    *(float4*)&so[w][lane * 4] = olo;
    *(float4*)&so[w][256 + lane * 4] = ohi;
    if (lane == 0) { sm[w] = m; sl[w] = l; }
    __syncthreads();

    const float M = fmaxf(fmaxf(sm[0], sm[1]), fmaxf(sm[2], sm[3]));
    float wt[4];
    float L = 0.f;
#pragma unroll
    for (int i = 0; i < 4; ++i) {
        wt[i] = (sl[i] > 0.f) ? __expf(sm[i] - M) : 0.f;
        L += sl[i] * wt[i];
    }
    const int t = threadIdx.x;
    const int idx = b * NSPLIT + chunk;
    float* PO = partO + (size_t)idx * H;
    PO[t]       = so[0][t] * wt[0] + so[1][t] * wt[1]
                + so[2][t] * wt[2] + so[3][t] * wt[3];
    PO[256 + t] = so[0][256 + t] * wt[0] + so[1][256 + t] * wt[1]
                + so[2][256 + t] * wt[2] + so[3][256 + t] * wt[3];
    if (t == 0) { partM[idx] = M; partL[idx] = L; }
}

// ---------------------------------------------------------------------------
// Kernel 3: combine partials -> c_t[b,:], cat=[c_t,h_t] in LDS, then
// out[b,i] = tanh(cat . W_r[i,:] + b_r[i]).  grid = (B, 2).
// ---------------------------------------------------------------------------
__global__ __launch_bounds__(256) void final_kernel(
    const float* __restrict__ partM, const float* __restrict__ partL,
    const float* __restrict__ partO, const float* __restrict__ h_t,
    const float* __restrict__ W_r, const float* __restrict__ b_r,
    float* __restrict__ out)
{
    const int b = blockIdx.x;
    const int half = blockIdx.y;
    const int t = threadIdx.x;
    __shared__ __align__(16) float cat[2 * H];

    float M = -INFINITY;
#pragma unroll
    for (int c = 0; c < NSPLIT; ++c)
        M = fmaxf(M, partM[b * NSPLIT + c]);

    float L = 0.f, O0 = 0.f, O1 = 0.f;
#pragma unroll 4
    for (int c = 0; c < NSPLIT; ++c) {
        const float lc = partL[b * NSPLIT + c];
        const float wc = (lc > 0.f) ? __expf(partM[b * NSPLIT + c] - M) : 0.f;
        const float* PO = partO + (size_t)(b * NSPLIT + c) * H;
        L += lc * wc;
        O0 += PO[t] * wc;
        O1 += PO[256 + t] * wc;
    }
    const float inv = 1.f / L;
    cat[t] = O0 * inv;
    cat[256 + t] = O1 * inv;
    cat[512 + t] = h_t[b * H + t];
    cat[768 + t] = h_t[b * H + 256 + t];
    __syncthreads();

    const int i = half * 256 + t;
    const float* wr = W_r + (size_t)i * (2 * H);
    float acc = b_r[i];
#pragma unroll 4
    for (int j = 0; j < 2 * H; j += 4) {
        const float4 wv = *(const float4*)&wr[j];
        acc += wv.x * cat[j] + wv.y * cat[j + 1]
             + wv.z * cat[j + 2] + wv.w * cat[j + 3];
    }
    out[b * H + i] = tanhf(acc);
}

// ---------------------------------------------------------------------------
extern "C" void kernel_launch(void* const* d_in, const int* in_sizes, int n_in,
                              void* d_out, int out_size, void* d_ws, size_t ws_size,
                              hipStream_t stream) {
    const float* hs  = (const float*)d_in[0];  // [S,B,H]
    const float* h_t = (const float*)d_in[1];  // [B,H]
    const int* mask  = (const int*)d_in[2];    // [B,S]
    const float* W_a = (const float*)d_in[3];  // [H,H]
    const float* b_a = (const float*)d_in[4];  // [H]
    const float* W_r = (const float*)d_in[5];  // [H,2H]
    const float* b_r = (const float*)d_in[6];  // [H]
    float* out = (float*)d_out;                // [B,H]
    float* ws = (float*)d_ws;

    // workspace (floats): v[B*H] | c0[64] | partM[B*NSPLIT] | partL[B*NSPLIT] | partO[B*NSPLIT*H]
    float* v     = ws;
    float* c0    = v + B * H;
    float* partM = c0 + 64;
    float* partL = partM + B * NSPLIT;
    float* partO = partL + B * NSPLIT;   // 16B-aligned: (32768+64+2048+2048)*4 % 16 == 0

    prep_kernel<<<dim3(B, 2), 256, 0, stream>>>(h_t, W_a, b_a, v, c0);
    pass_kernel<<<B * NSPLIT, 256, 0, stream>>>(hs, mask, v, c0, partM, partL, partO);
    final_kernel<<<dim3(B, 2), 256, 0, stream>>>(partM, partL, partO, h_t, W_r, b_r, out);
}